// Round 5
// baseline (682.202 us; speedup 1.0000x reference)
//
#include <hip/hip_runtime.h>

#define BB 256
#define TT 1024
#define II 3
#define HH 128
#define OO 3
#define BT 8              // batch elements per block
#define NBLK (BB / BT)    // 32 blocks
#define NT 384            // 6 waves: 4 MFMA + 2 aux (hid store + projection)
#define SH 136            // padded ushort stride per batch (+16B -> +4 banks)

typedef __attribute__((ext_vector_type(8))) short short8;   // 8 bf16
typedef __attribute__((ext_vector_type(4))) float f32x4;
typedef __attribute__((ext_vector_type(4))) unsigned int uint4v;
typedef __attribute__((ext_vector_type(2))) unsigned int uint2v;

#if __has_builtin(__builtin_amdgcn_exp2f)
#define EXP2F __builtin_amdgcn_exp2f
#else
#define EXP2F exp2f
#endif
#if __has_builtin(__builtin_amdgcn_rcpf)
#define RCPF __builtin_amdgcn_rcpf
#else
#define RCPF(x) (1.0f / (x))
#endif

__device__ __forceinline__ float fast_tanh(float x) {
    float e = EXP2F(x * 2.885390081777927f);
    return 1.0f - 2.0f * RCPF(e + 1.0f);
}

// LDS-only barrier: does not drain vmcnt, global stores/loads stay in flight.
__device__ __forceinline__ void bar_lds() {
    asm volatile("s_waitcnt lgkmcnt(0)\n\ts_barrier" ::: "memory");
}

template <int CTRL>
__device__ __forceinline__ float dpp_add(float p) {
    return p + __uint_as_float(__builtin_amdgcn_update_dpp(
        0, (int)__float_as_uint(p), CTRL, 0xF, 0xF, true));
}
#define DPP_XOR1 0xB1    // quad_perm [1,0,3,2]
#define DPP_XOR2 0x4E    // quad_perm [2,3,0,1]
#define DPP_HMIR 0x141   // row_half_mirror (lane^7 within 8)
#define DPP_MIRR 0x140   // row_mirror (lane -> 15-lane within 16)

// pack 2 f32 -> 2 bf16 (first arg in LOW 16 bits), HW RNE
__device__ __forceinline__ unsigned int bf16pk(float a, float b) {
    unsigned int r;
    asm("v_cvt_pk_bf16_f32 %0, %1, %2" : "=v"(r) : "v"(a), "v"(b));
    return r;
}
__device__ __forceinline__ float f_lo16(unsigned int p) { return __uint_as_float(p << 16); }
__device__ __forceinline__ float f_hi16(unsigned int p) { return __uint_as_float(p & 0xffff0000u); }

__device__ __forceinline__ f32x4 MFMA(uint4v a, uint4v b, f32x4 c) {
    return __builtin_amdgcn_mfma_f32_16x16x32_bf16(
        __builtin_bit_cast(short8, a), __builtin_bit_cast(short8, b), c, 0, 0, 0);
}

// 32 blocks, one per 8 batch elements. One s_barrier per timestep.
//
// Waves 0-3 (MFMA): wave wv owns rows [wv*32, wv*32+32) as two 16-row tiles.
//   s_{w+1} = tanh(W_hh @ s_w + W_ih @ x_w + b), split-bf16:
//   acc = Whi*hhi + Whi*hlo + Wlo*hhi, C-init = exact-fp32 xp (24 VALU FMA,
//   x streamed from global with 1-window register prefetch).
//   Layouts (round-3-verified): A lane&15=row, B lane&15=col(batch),
//   k=8*(lane>>4)+e; D col=lane&15, row=4*(lane>>4)+reg.
//   Hidden state lives ONLY as bf16 hi/lo in LDS; padded batch stride
//   SH=136 ushorts (272B == 4 banks mod 32) de-pathologizes all accesses.
// Waves 4-5 (aux): 4 batches each; lane (bb, hseg=lane&15) owns 8 h values.
//   Reads hi+lo (2 x b128), reconstructs fp32 (hi+lo, +-2^-18), stores
//   hid[w-1] (2 x f32x4, coalesced), projects out[w-1] (24 FMA + 12 DPP).
__global__ __launch_bounds__(NT) void rnn_kernel(
    const float* __restrict__ x,     // [B,T,I]
    const float* __restrict__ Wih,   // [H,I]
    const float* __restrict__ Whh,   // [H,H]
    const float* __restrict__ bih,   // [H]
    const float* __restrict__ bhh,   // [H]
    const float* __restrict__ h0,    // [1,H]
    const float* __restrict__ Wout,  // [O,H]
    const float* __restrict__ bout,  // [O]
    float* __restrict__ out,         // [B,T,O]
    float* __restrict__ hid)         // [B,T,H]
{
    __shared__ __align__(16) ushort Hhi[2][BT][SH];   // 4.25 KB
    __shared__ __align__(16) ushort Hlo[2][BT][SH];   // 4.25 KB

    const int tid = threadIdx.x;
    const int b0 = blockIdx.x * BT;
    const int wv = tid >> 6;
    const int lane = tid & 63;

    // ---- init s_0 = h0 (hi/lo split) ----
    for (int idx = tid; idx < BT * HH; idx += NT) {
        int bb = idx >> 7, h = idx & (HH - 1);
        float v = h0[h];
        unsigned int p = bf16pk(v, 0.f);
        float vh = f_lo16(p);
        unsigned int q = bf16pk(v - vh, 0.f);
        Hhi[0][bb][h] = (ushort)(p & 0xffffu);
        Hlo[0][bb][h] = (ushort)(q & 0xffffu);
    }

    if (wv < 4) {
        // ================= MFMA compute waves =================
        const int col  = lane & 15;
        const bool act = col < BT;
        const int colc = act ? col : (BT - 1);
        const int g    = lane >> 4;          // 0..3
        const int kb   = g * 8;              // k base within 32-chunk
        const int r0   = wv * 32 + g * 4;    // D rows base, tile 0

        // A fragments: W_hh rows, split hi/lo bf16
        uint4v Ahi[2][4], Alo[2][4];
#pragma unroll
        for (int tau = 0; tau < 2; ++tau) {
            const int row = wv * 32 + tau * 16 + col;
            const float* wrow = Whh + row * HH + kb;
#pragma unroll
            for (int c = 0; c < 4; ++c) {
                float4 wa = *(const float4*)(wrow + c * 32);
                float4 wb = *(const float4*)(wrow + c * 32 + 4);
                unsigned int h01 = bf16pk(wa.x, wa.y), h23 = bf16pk(wa.z, wa.w);
                unsigned int h45 = bf16pk(wb.x, wb.y), h67 = bf16pk(wb.z, wb.w);
                unsigned int l01 = bf16pk(wa.x - f_lo16(h01), wa.y - f_hi16(h01));
                unsigned int l23 = bf16pk(wa.z - f_lo16(h23), wa.w - f_hi16(h23));
                unsigned int l45 = bf16pk(wb.x - f_lo16(h45), wb.y - f_hi16(h45));
                unsigned int l67 = bf16pk(wb.z - f_lo16(h67), wb.w - f_hi16(h67));
                Ahi[tau][c] = uint4v{h01, h23, h45, h67};
                Alo[tau][c] = uint4v{l01, l23, l45, l67};
            }
        }

        // xp weights for this lane's 8 D rows (exact fp32 input projection)
        float wih[8][3], bias[8];
#pragma unroll
        for (int j = 0; j < 8; ++j) {
            const int r = r0 + (j >> 2) * 16 + (j & 3);
            wih[j][0] = Wih[r * II + 0];
            wih[j][1] = Wih[r * II + 1];
            wih[j][2] = Wih[r * II + 2];
            bias[j] = bih[r] + bhh[r];
        }

        const float* xb = x + (size_t)(b0 + colc) * TT * II;

        const ushort* rdHi[2] = { &Hhi[0][colc][kb], &Hhi[1][colc][kb] };
        const ushort* rdLo[2] = { &Hlo[0][colc][kb], &Hlo[1][colc][kb] };
        ushort* wrHi[2] = { &Hhi[1][colc][r0], &Hhi[0][colc][r0] };  // p writes p^1
        ushort* wrLo[2] = { &Hlo[1][colc][r0], &Hlo[0][colc][r0] };

        uint4v bh[4] = {}, bl[4] = {};   // inactive lanes keep zeros forever
        float xA0 = xb[0], xA1 = xb[1], xA2 = xb[2];
        float xB0 = 0.f, xB1 = 0.f, xB2 = 0.f;

        __syncthreads();

        auto win = [&](int w, int p, float x0, float x1, float x2,
                       float& n0, float& n1, float& n2) {
            // prefetch x for window w+1 (stays in flight across bar_lds)
            {
                const int wn = (w + 1 < TT) ? (w + 1) : (TT - 1);
                const float* xq = xb + (size_t)wn * II;
                n0 = xq[0]; n1 = xq[1]; n2 = xq[2];
            }
            if (act) {
#pragma unroll
                for (int c = 0; c < 4; ++c) {
                    bh[c] = *(const uint4v*)(rdHi[p] + c * 32);
                    bl[c] = *(const uint4v*)(rdLo[p] + c * 32);
                }
            }
            // exact-fp32 xp for the lane's 8 rows, as MFMA C-init
            float xpv[8];
#pragma unroll
            for (int j = 0; j < 8; ++j)
                xpv[j] = fmaf(x2, wih[j][2],
                         fmaf(x1, wih[j][1], fmaf(x0, wih[j][0], bias[j])));
            f32x4 a0 = {xpv[0], xpv[1], xpv[2], xpv[3]};
            f32x4 c0 = {xpv[4], xpv[5], xpv[6], xpv[7]};
            f32x4 a1 = {0.f, 0.f, 0.f, 0.f}, a2 = {0.f, 0.f, 0.f, 0.f};
            f32x4 c1 = {0.f, 0.f, 0.f, 0.f}, c2 = {0.f, 0.f, 0.f, 0.f};
#pragma unroll
            for (int c = 0; c < 4; ++c) {
                a0 = MFMA(Ahi[0][c], bh[c], a0);
                a1 = MFMA(Ahi[0][c], bl[c], a1);
                a2 = MFMA(Alo[0][c], bh[c], a2);
                c0 = MFMA(Ahi[1][c], bh[c], c0);
                c1 = MFMA(Ahi[1][c], bl[c], c1);
                c2 = MFMA(Alo[1][c], bh[c], c2);
            }
            f32x4 s0 = (a0 + a1) + a2;
            f32x4 s1 = (c0 + c1) + c2;
            float t0 = fast_tanh(s0.x), t1 = fast_tanh(s0.y);
            float t2 = fast_tanh(s0.z), t3 = fast_tanh(s0.w);
            float u0 = fast_tanh(s1.x), u1 = fast_tanh(s1.y);
            float u2 = fast_tanh(s1.z), u3 = fast_tanh(s1.w);
            if (act) {
                unsigned int p0 = bf16pk(t0, t1), p1 = bf16pk(t2, t3);
                unsigned int q0 = bf16pk(t0 - f_lo16(p0), t1 - f_hi16(p0));
                unsigned int q1 = bf16pk(t2 - f_lo16(p1), t3 - f_hi16(p1));
                *(uint2v*)(wrHi[p]) = uint2v{p0, p1};
                *(uint2v*)(wrLo[p]) = uint2v{q0, q1};
                unsigned int p2 = bf16pk(u0, u1), p3 = bf16pk(u2, u3);
                unsigned int q2 = bf16pk(u0 - f_lo16(p2), u1 - f_hi16(p2));
                unsigned int q3 = bf16pk(u2 - f_lo16(p3), u3 - f_hi16(p3));
                *(uint2v*)(wrHi[p] + 16) = uint2v{p2, p3};
                *(uint2v*)(wrLo[p] + 16) = uint2v{q2, q3};
            }
            bar_lds();
        };

        for (int w = 0; w < TT; w += 2) {
            win(w,     0, xA0, xA1, xA2, xB0, xB1, xB2);
            win(w + 1, 1, xB0, xB1, xB2, xA0, xA1, xA2);
        }
    } else {
        // ================= aux waves: hid store + projection =================
        const int a    = wv - 4;               // 0..1
        const int bb   = a * 4 + (lane >> 4);  // batch within block
        const int hseg = lane & 15;            // owns h = hseg*8 .. +8

        float wo[3][8];
#pragma unroll
        for (int o = 0; o < 3; ++o)
#pragma unroll
            for (int j = 0; j < 8; ++j) wo[o][j] = Wout[o * HH + hseg * 8 + j];
        const float bo0 = bout[0], bo1 = bout[1], bo2 = bout[2];

        float* hb = hid + ((size_t)(b0 + bb) * TT) * HH + hseg * 8;
        float* ob = out + (size_t)(b0 + bb) * TT * OO;
        const ushort* rdH[2] = { &Hhi[0][bb][hseg * 8], &Hhi[1][bb][hseg * 8] };
        const ushort* rdL[2] = { &Hlo[0][bb][hseg * 8], &Hlo[1][bb][hseg * 8] };

        __syncthreads();

        auto astore = [&](int t, int p) {
            uint4v uh = *(const uint4v*)rdH[p];
            uint4v ul = *(const uint4v*)rdL[p];
            float h0v = f_lo16(uh.x) + f_lo16(ul.x);
            float h1v = f_hi16(uh.x) + f_hi16(ul.x);
            float h2v = f_lo16(uh.y) + f_lo16(ul.y);
            float h3v = f_hi16(uh.y) + f_hi16(ul.y);
            float h4v = f_lo16(uh.z) + f_lo16(ul.z);
            float h5v = f_hi16(uh.z) + f_hi16(ul.z);
            float h6v = f_lo16(uh.w) + f_lo16(ul.w);
            float h7v = f_hi16(uh.w) + f_hi16(ul.w);
            float* g = hb + (size_t)t * HH;
            *(f32x4*)(g)     = f32x4{h0v, h1v, h2v, h3v};
            *(f32x4*)(g + 4) = f32x4{h4v, h5v, h6v, h7v};
            float p0 = 0.f, p1 = 0.f, p2 = 0.f;
            p0 = fmaf(wo[0][0], h0v, p0); p0 = fmaf(wo[0][1], h1v, p0);
            p0 = fmaf(wo[0][2], h2v, p0); p0 = fmaf(wo[0][3], h3v, p0);
            p0 = fmaf(wo[0][4], h4v, p0); p0 = fmaf(wo[0][5], h5v, p0);
            p0 = fmaf(wo[0][6], h6v, p0); p0 = fmaf(wo[0][7], h7v, p0);
            p1 = fmaf(wo[1][0], h0v, p1); p1 = fmaf(wo[1][1], h1v, p1);
            p1 = fmaf(wo[1][2], h2v, p1); p1 = fmaf(wo[1][3], h3v, p1);
            p1 = fmaf(wo[1][4], h4v, p1); p1 = fmaf(wo[1][5], h5v, p1);
            p1 = fmaf(wo[1][6], h6v, p1); p1 = fmaf(wo[1][7], h7v, p1);
            p2 = fmaf(wo[2][0], h0v, p2); p2 = fmaf(wo[2][1], h1v, p2);
            p2 = fmaf(wo[2][2], h2v, p2); p2 = fmaf(wo[2][3], h3v, p2);
            p2 = fmaf(wo[2][4], h4v, p2); p2 = fmaf(wo[2][5], h5v, p2);
            p2 = fmaf(wo[2][6], h6v, p2); p2 = fmaf(wo[2][7], h7v, p2);
            p0 = dpp_add<DPP_XOR1>(p0); p0 = dpp_add<DPP_XOR2>(p0);
            p0 = dpp_add<DPP_HMIR>(p0); p0 = dpp_add<DPP_MIRR>(p0);
            p1 = dpp_add<DPP_XOR1>(p1); p1 = dpp_add<DPP_XOR2>(p1);
            p1 = dpp_add<DPP_HMIR>(p1); p1 = dpp_add<DPP_MIRR>(p1);
            p2 = dpp_add<DPP_XOR1>(p2); p2 = dpp_add<DPP_XOR2>(p2);
            p2 = dpp_add<DPP_HMIR>(p2); p2 = dpp_add<DPP_MIRR>(p2);
            if (hseg == 0) {
                float* o = ob + (size_t)t * OO;
                o[0] = p0 + bo0;
                o[1] = p1 + bo1;
                o[2] = p2 + bo2;
            }
        };

        // Barrier ledger: exactly TT bar_lds in the loop (2 per iteration),
        // matching the MFMA waves' TT. During even window w the stable buffer
        // is buf0 = s_w (valid for w>0: s_w = hid[w-1]); during odd window
        // w+1 it is buf1 = s_{w+1} = hid[w].
        for (int w = 0; w < TT; w += 2) {
            if (w > 0) astore(w - 1, 0);
            bar_lds();
            astore(w, 1);
            bar_lds();
        }
        // tail: after the last barrier buf0 = s_TT = hid[TT-1]; compute waves
        // are done writing, no further sync needed.
        astore(TT - 1, 0);
    }
}

extern "C" void kernel_launch(void* const* d_in, const int* in_sizes, int n_in,
                              void* d_out, int out_size, void* d_ws, size_t ws_size,
                              hipStream_t stream) {
    const float* x    = (const float*)d_in[0];  // [256,1024,3]
    const float* Wih  = (const float*)d_in[1];  // [128,3]
    const float* Whh  = (const float*)d_in[2];  // [128,128]
    const float* bih  = (const float*)d_in[3];  // [128]
    const float* bhh  = (const float*)d_in[4];  // [128]
    const float* h0   = (const float*)d_in[5];  // [1,128]
    const float* Wout = (const float*)d_in[6];  // [3,128]
    const float* bout = (const float*)d_in[7];  // [3]

    float* out = (float*)d_out;                 // [B,T,O] first
    float* hid = out + (size_t)BB * TT * OO;    // then [B,T,H]

    rnn_kernel<<<NBLK, NT, 0, stream>>>(x, Wih, Whh, bih, bhh, h0, Wout, bout, out, hid);
}

// Round 6
// 470.133 us; speedup vs baseline: 1.4511x; 1.4511x over previous
//
#include <hip/hip_runtime.h>

#define BB 256
#define TT 1024
#define II 3
#define HH 128
#define OO 3
#define NT 576   // 8 compute waves (512 thr) + 1 store/projection wave (64 thr)

#if __has_builtin(__builtin_amdgcn_exp2f)
#define EXP2F __builtin_amdgcn_exp2f
#else
#define EXP2F exp2f
#endif
#if __has_builtin(__builtin_amdgcn_rcpf)
#define RCPF __builtin_amdgcn_rcpf
#else
#define RCPF(x) (1.0f / (x))
#endif

// tanh(x) = 1 - 2/(e^{2x}+1)
__device__ __forceinline__ float fast_tanh(float x) {
    float e = EXP2F(x * 2.885390081777927f);
    return 1.0f - 2.0f * RCPF(e + 1.0f);
}

// Workgroup barrier that fences LDS only — does NOT drain vmcnt, so global
// stores stay in flight across it. All cross-wave dataflow goes through LDS.
__device__ __forceinline__ void bar_lds() {
    asm volatile("s_waitcnt lgkmcnt(0)\n\ts_barrier" ::: "memory");
}

// p += p(lane ^ pattern) via DPP (pure VALU; keeps the reduce off the LDS pipe)
template <int CTRL>
__device__ __forceinline__ float dpp_add(float p) {
    return p + __uint_as_float(__builtin_amdgcn_update_dpp(
        0, (int)__float_as_uint(p), CTRL, 0xF, 0xF, true));
}
#define DPP_XOR1 0xB1   // quad_perm [1,0,3,2]
#define DPP_XOR2 0x4E   // quad_perm [2,3,0,1]
#define DPP_HMIR 0x141  // row_half_mirror: lane^7 within 8-lane halves
#define DPP_MIRR 0x140  // row_mirror: lane^15 within 16-lane rows

// sum over 4-lane quad via DPP quad_perm (store wave)
__device__ __forceinline__ float quad_reduce(float p) {
    p = dpp_add<DPP_XOR1>(p);
    p = dpp_add<DPP_XOR2>(p);
    return p;
}

// Physical storage permutation for the 128-float hidden state, at float4-chunk
// granularity: logical chunk c (0..31) lives at physical chunk psi(c).
// Readers fetch logical chunks {2s, 2s+1} -> physical {s, s+16}: within each
// 16-lane row the 16 addresses stride 16B -> banks 4s mod 32, 2 words/bank
// (the floor; 2-way is free per m136). Without psi the stride would be 32B ->
// 4-way. All other access patterns audited <=2-way.
__device__ __forceinline__ int psi(int c) { return (c >> 1) | ((c & 1) << 4); }

// One block per batch element; one s_barrier per timestep (latency-bound:
// wall time = 1024 * per-step critical path).
//
// Compute: 8 waves. Wave wv, lane l: og = l>>4 (row), s = l&15 (K-segment).
//   Lane accumulates FOUR outputs o = wv*16+og*4+{0..3} over K-chunk
//   [8s, 8s+8) — one h-read feeds 4 outputs (16KB/step LDS broadcast
//   traffic, half of round 2's No=2). Reduce: 3 DPP levels (xor1,xor2,
//   half_mirror) on each of the 4 accumulators -> per-8-half sums; then a
//   distributed finisher: lane with u = s^(15*(s>>3)) < 4 selects output u,
//   one row_mirror DPP-add completes the 16-lane sum, adds the exact-fp32
//   input projection, tanh, single b32 write (lanes s<4).
// Wave 8: hid/out stores, projection pipelined across 2 barrier windows
//   (phase A: MACs + DPP quad-reduce -> LDS partials; phase B next window).
__global__ __launch_bounds__(NT) void rnn_kernel(
    const float* __restrict__ x,     // [B,T,I]
    const float* __restrict__ Wih,   // [H,I]
    const float* __restrict__ Whh,   // [H,H]
    const float* __restrict__ bih,   // [H]
    const float* __restrict__ bhh,   // [H]
    const float* __restrict__ h0,    // [1,H]
    const float* __restrict__ Wout,  // [O,H]
    const float* __restrict__ bout,  // [O]
    float* __restrict__ out,         // [B,T,O]
    float* __restrict__ hid)         // [B,T,H]
{
    __shared__ __align__(16) float4 xs[TT];       // (x0,x1,x2,pad) per t
    __shared__ __align__(16) float hbuf[2][HH];   // double-buffered hidden (psi layout)
    __shared__ __align__(16) float psum[2][OO * 16];  // projection partials

    const int tid = threadIdx.x;
    const int b = blockIdx.x;

    // --- stage inputs; init h(0) in psi layout ---
    const float* xb = x + (size_t)b * TT * II;
    for (int idx = tid; idx < TT * II; idx += NT) {
        int t = idx / 3;
        int c = idx - t * 3;
        ((float*)&xs[t])[c] = xb[idx];
    }
    if (tid < HH) hbuf[0][4 * psi(tid >> 2) + (tid & 3)] = h0[tid];

    if (tid < 512) {
        // ================= compute waves =================
        const int lane = tid & 63;
        const int wv   = tid >> 6;       // wave 0..7
        const int og   = lane >> 4;      // output-group (16-lane DPP row) 0..3
        const int s    = lane & 15;      // K-segment: k in [8s, 8s+8)
        const int obase = wv * 16 + og * 4;
        const int u    = s ^ (15 * (s >> 3));  // mirror-symmetric finisher id

        // W_hh[obase+j][8s .. 8s+8] for j=0..3 (32 VGPRs)
        float w[4][8];
#pragma unroll
        for (int j = 0; j < 4; ++j) {
            const float* wr = Whh + (size_t)(obase + j) * HH + 8 * s;
            float4 v1 = ((const float4*)wr)[0];
            float4 v2 = ((const float4*)wr)[1];
            w[j][0] = v1.x; w[j][1] = v1.y; w[j][2] = v1.z; w[j][3] = v1.w;
            w[j][4] = v2.x; w[j][5] = v2.y; w[j][6] = v2.z; w[j][7] = v2.w;
        }
        // finisher lane's input-projection row (u<4 lanes use it; clamp rest)
        const int ru = obase + (u & 3);
        const float wiu0 = Wih[ru * II + 0];
        const float wiu1 = Wih[ru * II + 1];
        const float wiu2 = Wih[ru * II + 2];
        const float biasu = bih[ru] + bhh[ru];
        // write slot for lane s<4: logical h = obase+s -> chunk wv*4+og, elem s
        const int wpos = 4 * psi(wv * 4 + og) + s;

        bar_lds();

        auto cstep = [&](int t, const float* hcur, float* hnext) {
            // logical h[8s..8s+4] and h[8s+4..8s+8] through psi layout
            float4 h1 = ((const float4*)hcur)[s];
            float4 h2 = ((const float4*)hcur)[16 + s];
            // 4 outputs x 8 MACs, paired even/odd to invite v_pk_fma_f32
            float a0e = 0.f, a0o = 0.f, a1e = 0.f, a1o = 0.f;
            float a2e = 0.f, a2o = 0.f, a3e = 0.f, a3o = 0.f;
            a0e = fmaf(w[0][0], h1.x, a0e); a0o = fmaf(w[0][1], h1.y, a0o);
            a0e = fmaf(w[0][2], h1.z, a0e); a0o = fmaf(w[0][3], h1.w, a0o);
            a0e = fmaf(w[0][4], h2.x, a0e); a0o = fmaf(w[0][5], h2.y, a0o);
            a0e = fmaf(w[0][6], h2.z, a0e); a0o = fmaf(w[0][7], h2.w, a0o);
            a1e = fmaf(w[1][0], h1.x, a1e); a1o = fmaf(w[1][1], h1.y, a1o);
            a1e = fmaf(w[1][2], h1.z, a1e); a1o = fmaf(w[1][3], h1.w, a1o);
            a1e = fmaf(w[1][4], h2.x, a1e); a1o = fmaf(w[1][5], h2.y, a1o);
            a1e = fmaf(w[1][6], h2.z, a1e); a1o = fmaf(w[1][7], h2.w, a1o);
            a2e = fmaf(w[2][0], h1.x, a2e); a2o = fmaf(w[2][1], h1.y, a2o);
            a2e = fmaf(w[2][2], h1.z, a2e); a2o = fmaf(w[2][3], h1.w, a2o);
            a2e = fmaf(w[2][4], h2.x, a2e); a2o = fmaf(w[2][5], h2.y, a2o);
            a2e = fmaf(w[2][6], h2.z, a2e); a2o = fmaf(w[2][7], h2.w, a2o);
            a3e = fmaf(w[3][0], h1.x, a3e); a3o = fmaf(w[3][1], h1.y, a3o);
            a3e = fmaf(w[3][2], h1.z, a3e); a3o = fmaf(w[3][3], h1.w, a3o);
            a3e = fmaf(w[3][4], h2.x, a3e); a3o = fmaf(w[3][5], h2.y, a3o);
            a3e = fmaf(w[3][6], h2.z, a3e); a3o = fmaf(w[3][7], h2.w, a3o);
            float a0 = a0e + a0o, a1 = a1e + a1o;
            float a2 = a2e + a2o, a3 = a3e + a3o;
            // 3 DPP levels -> each 8-lane half holds its half-sum
            a0 = dpp_add<DPP_XOR1>(a0); a0 = dpp_add<DPP_XOR2>(a0); a0 = dpp_add<DPP_HMIR>(a0);
            a1 = dpp_add<DPP_XOR1>(a1); a1 = dpp_add<DPP_XOR2>(a1); a1 = dpp_add<DPP_HMIR>(a1);
            a2 = dpp_add<DPP_XOR1>(a2); a2 = dpp_add<DPP_XOR2>(a2); a2 = dpp_add<DPP_HMIR>(a2);
            a3 = dpp_add<DPP_XOR1>(a3); a3 = dpp_add<DPP_XOR2>(a3); a3 = dpp_add<DPP_HMIR>(a3);
            // distributed finish: lane u selects output u; row_mirror pairs
            // lane s with s^15 (same u in the other half) -> full 16-lane sum
            float asel = a0;
            asel = (u == 1) ? a1 : asel;
            asel = (u == 2) ? a2 : asel;
            asel = (u == 3) ? a3 : asel;
            asel = dpp_add<DPP_MIRR>(asel);
            float4 xv = xs[t];  // wave-uniform broadcast
            float xp = fmaf(xv.z, wiu2, fmaf(xv.y, wiu1, fmaf(xv.x, wiu0, biasu)));
            float val = fast_tanh(asel + xp);
            if (s < 4) hnext[wpos] = val;
            bar_lds();
        };

        for (int t = 0; t < TT; t += 2) {
            cstep(t, hbuf[0], hbuf[1]);
            cstep(t + 1, hbuf[1], hbuf[0]);
        }
    } else {
        // ================= store + projection wave =================
        const int L = tid - 512;  // lane 0..63; owns logical h = 2L, 2L+1
        const float w00 = Wout[0 * HH + 2 * L], w01 = Wout[0 * HH + 2 * L + 1];
        const float w10 = Wout[1 * HH + 2 * L], w11 = Wout[1 * HH + 2 * L + 1];
        const float w20 = Wout[2 * HH + 2 * L], w21 = Wout[2 * HH + 2 * L + 1];
        const float bL = (L == 0) ? bout[0] : (L == 1) ? bout[1]
                       : (L == 2) ? bout[2] : 0.f;
        float* ob = out + (size_t)b * TT * OO;
        float* hb = hid + (size_t)b * TT * HH;
        const int q = L >> 2;               // quad id 0..15
        const bool qlead = (L & 3) == 0;
        // logical h[2L] through psi layout (float2-aligned)
        const int fpos = 4 * psi(L >> 1) + 2 * (L & 1);

        bar_lds();

        auto sstep = [&](int t, const float* hcur, float* psA, const float* psB) {
            // phase A: hid[t-1] store + quad partials for out[t-1] -> psA
            if (t >= 1) {
                const float2 hv = *(const float2*)(hcur + fpos);
                ((float2*)(hb + (size_t)(t - 1) * HH))[L] = hv;  // coalesced 512B
                float p0 = fmaf(hv.x, w00, hv.y * w01);
                float p1 = fmaf(hv.x, w10, hv.y * w11);
                float p2 = fmaf(hv.x, w20, hv.y * w21);
                p0 = quad_reduce(p0);
                p1 = quad_reduce(p1);
                p2 = quad_reduce(p2);
                if (qlead) {
                    psA[0 * 16 + q] = p0;
                    psA[1 * 16 + q] = p1;
                    psA[2 * 16 + q] = p2;
                }
            }
            // phase B: finish out[t-2] from previous window's partials (psB).
            if (t >= 2 && L < OO) {
                const float4* pp = (const float4*)(psB + L * 16);
                float4 u0 = pp[0], u1 = pp[1], u2 = pp[2], u3 = pp[3];
                float s0 = ((u0.x + u0.y) + (u0.z + u0.w)) +
                           ((u1.x + u1.y) + (u1.z + u1.w));
                float s1 = ((u2.x + u2.y) + (u2.z + u2.w)) +
                           ((u3.x + u3.y) + (u3.z + u3.w));
                ob[(size_t)(t - 2) * OO + L] = s0 + s1 + bL;
            }
            bar_lds();
        };

        for (int t = 0; t < TT; t += 2) {
            sstep(t, hbuf[0], psum[0], psum[1]);
            sstep(t + 1, hbuf[1], psum[1], psum[0]);
        }

        // tail (no barriers; compute waves exited, barrier counts match):
        // hbuf[0] = h[TT], psum[1] holds partials for out[TT-2].
        {
            const float2 hv = *(const float2*)(&hbuf[0][0] + fpos);
            ((float2*)(hb + (size_t)(TT - 1) * HH))[L] = hv;
            float p0 = fmaf(hv.x, w00, hv.y * w01);
            float p1 = fmaf(hv.x, w10, hv.y * w11);
            float p2 = fmaf(hv.x, w20, hv.y * w21);
            p0 = quad_reduce(p0);
            p1 = quad_reduce(p1);
            p2 = quad_reduce(p2);
            if (qlead) {
                psum[0][0 * 16 + q] = p0;
                psum[0][1 * 16 + q] = p1;
                psum[0][2 * 16 + q] = p2;
            }
            if (L < OO) {
                const float4* pp = (const float4*)(psum[1] + L * 16);
                float4 u0 = pp[0], u1 = pp[1], u2 = pp[2], u3 = pp[3];
                float s0 = ((u0.x + u0.y) + (u0.z + u0.w)) +
                           ((u1.x + u1.y) + (u1.z + u1.w));
                float s1 = ((u2.x + u2.y) + (u2.z + u2.w)) +
                           ((u3.x + u3.y) + (u3.z + u3.w));
                ob[(size_t)(TT - 2) * OO + L] = s0 + s1 + bL;
                const float4* pq = (const float4*)(psum[0] + L * 16);
                float4 v0 = pq[0], v1 = pq[1], v2 = pq[2], v3 = pq[3];
                float r0 = ((v0.x + v0.y) + (v0.z + v0.w)) +
                           ((v1.x + v1.y) + (v1.z + v1.w));
                float r1 = ((v2.x + v2.y) + (v2.z + v2.w)) +
                           ((v3.x + v3.y) + (v3.z + v3.w));
                ob[(size_t)(TT - 1) * OO + L] = r0 + r1 + bL;
            }
        }
    }
}

extern "C" void kernel_launch(void* const* d_in, const int* in_sizes, int n_in,
                              void* d_out, int out_size, void* d_ws, size_t ws_size,
                              hipStream_t stream) {
    const float* x    = (const float*)d_in[0];  // [256,1024,3]
    const float* Wih  = (const float*)d_in[1];  // [128,3]
    const float* Whh  = (const float*)d_in[2];  // [128,128]
    const float* bih  = (const float*)d_in[3];  // [128]
    const float* bhh  = (const float*)d_in[4];  // [128]
    const float* h0   = (const float*)d_in[5];  // [1,128]
    const float* Wout = (const float*)d_in[6];  // [3,128]
    const float* bout = (const float*)d_in[7];  // [3]

    float* out = (float*)d_out;                 // [B,T,O] first
    float* hid = out + (size_t)BB * TT * OO;    // then [B,T,H]

    rnn_kernel<<<BB, NT, 0, stream>>>(x, Wih, Whh, bih, bhh, h0, Wout, bout, out, hid);
}